// Round 10
// baseline (282.271 us; speedup 1.0000x reference)
//
#include <hip/hip_runtime.h>

typedef unsigned short u16;
typedef unsigned int u32;
typedef __bf16 bf16x8 __attribute__((ext_vector_type(8)));
typedef float f32x4 __attribute__((ext_vector_type(4)));

#define HP 258
// weight-table element offsets within ws (u16 units)
#define E_WT0 0
#define E_WT1 37120
#define E_WT2 46592
#define E_WTF 56064
// ---- per-batch strided layout: all 4 batches resident simultaneously ----
// 258*258 = 66564 pixels. inpT is CHUNK-MAJOR [4 ch-chunks][66564 px][32 ch] bf16.
#define C_CH      4260096ull             // one chunk = 66564*32*2 B
#define OFF_INPT  131072ull
#define S_INPT    17040384ull            // 4*C_CH
#define OFF_HT    68292608ull            // OFF_INPT + 4*S_INPT
#define S_H       4260096ull             // 66564*32*2
#define OFF_T1    85332992ull            // OFF_HT + 4*S_H
#define OFF_FEA   102373376ull           // OFF_T1 + 4*S_H
#define OFF_XREFT 119413760ull           // OFF_FEA + 4*S_H
#define S_XREF    4194304ull             // 256*256*32*2
#define OFF_XNBT  136190976ull           // OFF_XREFT + 4*S_XREF
#define S_XNB     4595712ull             // 264*272*32*2
#define WS_NEED   154573824ull           // OFF_XNBT + 4*S_XNB  (ws is 256 MiB per R2 fill evidence)
// u16-element strides
#define SE_INPT 8520192u
#define SE_H    2130048u
#define SE_XREF 2097152u
#define SE_XNB  2297856u

__device__ __forceinline__ float bf2f(u16 u){ u32 x = ((u32)u) << 16; return __builtin_bit_cast(float, x); }
__device__ __forceinline__ u16 f2bf(float f){
  u32 x = __builtin_bit_cast(u32, f);
  return (u16)((x + 0x7fffu + ((x >> 16) & 1u)) >> 16);   // RNE
}
__device__ __forceinline__ u32 pack2(float a, float b){ return (u32)f2bf(a) | ((u32)f2bf(b) << 16); }
__device__ __forceinline__ float lrelu(float x){ return x >= 0.f ? x : 0.1f * x; }

__global__ void k_sent(float* __restrict__ out, float val){
  if (threadIdx.x == 0 && blockIdx.x == 0) out[0] = val;
}

// ---------------- fused prep: xpose | up | halo | wprep (independent, disjoint outputs) -------
// R18: one launch replaces 4. Roles by block range (uniform per block):
//   [0,2146)    xpose, wave-mapped: wave wvi = bxx*4 + wv; 0..4095 ref rows, 4096..8583 nb padded
//   [2146,2402) up: 1 row per block, thread = 1 px, all 34 ch (contiguous 64 B line store)
//   [2402,2663) halo-ring zeroing
//   [2663,2679) wprep (bio==0 only), grid-stride
__global__ __launch_bounds__(256) void k_prep(const float* __restrict__ xref,
    const float* __restrict__ xnb, const float* __restrict__ bflow,
    const float* __restrict__ bfeat, const float* __restrict__ w0,
    const float* __restrict__ w1, const float* __restrict__ w2,
    const float* __restrict__ wf, char* __restrict__ ws){
  const int tid = threadIdx.x;
  const int bxx = blockIdx.x;
  const int bio = blockIdx.y;

  if (bxx < 2146){
    // ---- xpose: [c][h][w] fp32 -> [h][w][c] bf16; 4 thr/px, 8 ch/thr ----
    u16* xrefT0 = (u16*)(ws + OFF_XREFT);
    u16* xnbT0  = (u16*)(ws + OFF_XNBT);
    const int wvi = bxx * 4 + (tid >> 6);
    const int l = tid & 63;
    const int cq = l & 3, c0 = cq * 8;
    float v[8];
    u32 p[4];
    if (wvi < 4096){
      const int row = wvi >> 4;
      const int px = ((wvi & 15) << 4) + (l >> 2);
      const float* src = xref + ((size_t)(bio * 32 + c0)) * 65536 + (size_t)row * 256 + px;
      #pragma unroll
      for (int k = 0; k < 8; k++) v[k] = src[(size_t)k * 65536];
      #pragma unroll
      for (int j = 0; j < 4; j++) p[j] = pack2(v[2 * j], v[2 * j + 1]);
      *(uint4*)(xrefT0 + (size_t)bio * SE_XREF + ((size_t)row * 256 + px) * 32 + c0) = *(uint4*)p;
    } else {
      const int i = wvi - 4096;                // 0..4487 = 264 rows x 17 px-groups
      const int hp = i / 17, pg = i - hp * 17;
      const int pt = pg * 16 + (l >> 2);
      const int ih = hp - 4, px = pt - 4;
      u16* dst = xnbT0 + (size_t)bio * SE_XNB + ((size_t)hp * 272 + pt) * 32 + c0;
      if (ih >= 0 && ih <= 255 && px >= 0 && px <= 255){
        const float* src = xnb + ((size_t)(bio * 32 + c0)) * 65536 + (size_t)ih * 256 + px;
        #pragma unroll
        for (int k = 0; k < 8; k++) v[k] = src[(size_t)k * 65536];
        #pragma unroll
        for (int j = 0; j < 4; j++) p[j] = pack2(v[2 * j], v[2 * j + 1]);
        *(uint4*)dst = *(uint4*)p;
      } else {
        uint4 z = make_uint4(0u, 0u, 0u, 0u);
        *(uint4*)dst = z;
      }
    }
  } else if (bxx < 2402){
    // ---- bilinear 2x upsample (ch 0..33) + zero tail ----
    const int ubx = bxx - 2146;
    const int w = tid;
    const int h = (ubx & 7) * 32 + (ubx >> 3);   // XCD swizzle
    int y0 = (h >> 1) - 1 + (h & 1);
    const float fy = (h & 1) ? 0.25f : 0.75f;
    const int y0o = (y0 < 0 ? 0 : y0) * 128;
    const int y1o = ((y0 + 1) > 127 ? 127 : (y0 + 1)) * 128;
    int x0 = (w >> 1) - 1 + (w & 1);
    const float fx = (w & 1) ? 0.25f : 0.75f;
    const int x0c = x0 < 0 ? 0 : x0;
    const int x1c = (x0 + 1) > 127 ? 127 : (x0 + 1);
    char* pxb = ws + OFF_INPT + (size_t)bio * S_INPT + ((size_t)(h + 1) * 258 + (w + 1)) * 64;
    u32 pk[16];
    #pragma unroll
    for (int d = 0; d < 16; d++){
      float vv[2];
      #pragma unroll
      for (int e = 0; e < 2; e++){
        const float* pl = bfeat + ((size_t)(bio * 32 + 2 * d + e)) * 16384;
        float v00 = pl[y0o + x0c], v01 = pl[y0o + x1c];
        float v10 = pl[y1o + x0c], v11 = pl[y1o + x1c];
        float r0 = v00 + fx * (v01 - v00);
        float r1 = v10 + fx * (v11 - v10);
        vv[e] = r0 + fy * (r1 - r0);
      }
      pk[d] = pack2(vv[0], vv[1]);
    }
    uint4* dst0 = (uint4*)pxb;
    #pragma unroll
    for (int q = 0; q < 4; q++) dst0[q] = ((uint4*)pk)[q];
    float fv[2];
    #pragma unroll
    for (int e = 0; e < 2; e++){
      const float* pl = bflow + ((size_t)(bio * 2 + e)) * 16384;
      float v00 = pl[y0o + x0c], v01 = pl[y0o + x1c];
      float v10 = pl[y1o + x0c], v11 = pl[y1o + x1c];
      float r0 = v00 + fx * (v01 - v00);
      float r1 = v10 + fx * (v11 - v10);
      fv[e] = (r0 + fy * (r1 - r0)) * 2.f;
    }
    *(u32*)(pxb + C_CH) = pack2(fv[0], fv[1]);
    *(u16*)(pxb + 3 * C_CH + 38) = 0;
    #pragma unroll
    for (int k2 = 0; k2 < 6; k2++) *(u32*)(pxb + 3 * C_CH + 40 + 4 * k2) = 0;
  } else if (bxx < 2663){
    // ---- halo-ring zeroing ----
    int idx = (bxx - 2402) * 256 + tid;
    if (idx >= 258 * 258) return;
    int y = idx / 258;
    int x = idx - y * 258;
    if (y != 0 && y != 257 && x != 0 && x != 257) return;
    uint4 z = make_uint4(0u, 0u, 0u, 0u);
    size_t pix = (size_t)idx;
    #pragma unroll
    for (int s = 0; s < 4; s++){
      uint4* q0 = (uint4*)(ws + OFF_INPT + (size_t)bio * S_INPT + (size_t)s * C_CH + pix * 64);
      #pragma unroll
      for (int k = 0; k < 4; k++) q0[k] = z;
    }
    uint4* q1 = (uint4*)(ws + OFF_HT  + (size_t)bio * S_H + pix * 64);
    uint4* q2 = (uint4*)(ws + OFF_T1  + (size_t)bio * S_H + pix * 64);
    uint4* q3 = (uint4*)(ws + OFF_FEA + (size_t)bio * S_H + pix * 64);
    #pragma unroll
    for (int k = 0; k < 4; k++){ q1[k] = z; q2[k] = z; q3[k] = z; }
  } else {
    // ---- wprep (batch-independent; bio 0 only) ----
    if (bio != 0) return;
    u16* wse = (u16*)ws;
    for (int idx = (bxx - 2663) * 256 + tid; idx < 60800; idx += 4096){
      float v = 0.f;
      if (idx < 37120){                       // Wt0: 32 rows x 1160 (K=9*128=1152 used)
        int co = idx / 1160, kk = idx % 1160;
        if (kk < 1152){
          int tap = kk >> 7, c = kk & 127;
          if (c < 115){
            int oc = (c < 34) ? (81 + c) : (c - 34);
            v = w0[(co * 115 + oc) * 9 + tap];
          }
        }
      } else if (idx < 46592){                // Wt1: 32 x 296 (K=9*32=288)
        int r = idx - 37120; int co = r / 296, kk = r % 296;
        if (kk < 288){ int tap = kk >> 5, c = kk & 31; v = w1[(co * 32 + c) * 9 + tap]; }
      } else if (idx < 56064){                // Wt2
        int r = idx - 46592; int co = r / 296, kk = r % 296;
        if (kk < 288){ int tap = kk >> 5, c = kk & 31; v = w2[(co * 32 + c) * 9 + tap]; }
      } else {                                // Wtf: 16 x 296, rows 3..15 zero
        int r = idx - 56064; int co = r / 296, kk = r % 296;
        if (kk < 288 && co < 3){ int tap = kk >> 5, c = kk & 31; v = wf[(co * 32 + c) * 9 + tap]; }
      }
      wse[idx] = f2bf(v);
    }
  }
}

// ---------------- MFMA correlation: D[m][n] = sum_c ref[c][w0+m] * nb[c][ih][w0+n-4] ----------
// Per wave: 16 px, all 9 dy x 9 dx. Epilogue: predicated 2B stores into chunk-major inpT.
__global__ __launch_bounds__(256) void k_corr_mfma(const u16* __restrict__ xrefT0,
    const u16* __restrict__ xnbT0, char* __restrict__ ws){
  const int tid = threadIdx.x;
  const int wv = tid >> 6, l = tid & 63;
  const int bx = blockIdx.x;
  const int bio = blockIdx.y;
  const u16* xrefT = xrefT0 + (size_t)bio * SE_XREF;
  const u16* xnbT  = xnbT0  + (size_t)bio * SE_XNB;
  const int r = bx & 255, sub = bx >> 8;
  const int h = (r & 7) * 32 + (r >> 3);     // XCD swizzle: nbT row reuse stays on-XCD
  const int w0 = (sub * 4 + wv) * 16;
  const int m16 = l & 15, g = l >> 4;

  uint4 ua = *(const uint4*)(xrefT + ((size_t)h * 256 + w0 + m16) * 32 + g * 8);
  bf16x8 av = __builtin_bit_cast(bf16x8, ua);

  size_t bOff = ((size_t)h * 272 + w0 + m16) * 32 + g * 8;
  char* ob = ws + OFF_INPT + (size_t)bio * S_INPT
             + ((size_t)(h + 1) * 258 + (w0 + 1) + g * 4) * 64;
  const f32x4 z = {0.f, 0.f, 0.f, 0.f};
  #pragma unroll
  for (int dy = 0; dy < 9; dy++){
    uint4 ub0 = *(const uint4*)(xnbT + bOff);
    uint4 ub1 = *(const uint4*)(xnbT + bOff + 512);
    bOff += 8704;                            // next padded row (272*32)
    f32x4 d0 = __builtin_amdgcn_mfma_f32_16x16x32_bf16(av, __builtin_bit_cast(bf16x8, ub0), z, 0, 0, 0);
    f32x4 d1 = __builtin_amdgcn_mfma_f32_16x16x32_bf16(av, __builtin_bit_cast(bf16x8, ub1), z, 0, 0, 0);
    #pragma unroll
    for (int j = 0; j < 4; j++){
      int dxa = m16 - g * 4 - j;             // frag0: dx = n - m
      int dxb = dxa + 16;                    // frag1: dx = n + 16 - m
      bool va = (unsigned)dxa <= 8u;
      bool vb = (unsigned)dxb <= 8u;
      if (va | vb){
        float val = va ? d0[j] : d1[j];
        int dx = va ? dxa : dxb;
        float f = lrelu(val * 0.03125f);
        int c = 34 + dy * 9 + dx;            // chunk-major channel
        *(u16*)(ob + j * 64 + (size_t)(c >> 5) * C_CH + (c & 31) * 2) = f2bf(f);
      }
    }
  }
}

// ---------------- conv0: 128->32, LDS-staged input (s-chunked), weights from global(L2) ------
// R17 geometry (4 rows x 64 px, 25.3 KB LDS) + R18 XOR bank swizzle:
// 16B unit (pxi,cq) stored at unit index (row*66+pxi)*4 + (cq ^ ((pxi>>1)&3)) -> 16-lane
// ds_read_b128 hits 8 distinct bank-bases (2 lanes/bank = free) vs 2 (8-way) unswizzled.
__global__ __launch_bounds__(256) void k_conv0(const u16* __restrict__ inT0, const u16* __restrict__ wt,
    const float* __restrict__ bias, u16* __restrict__ outA0){
  __shared__ __align__(16) u16 inL[12672];       // [6][66][32]
  const int tid = threadIdx.x;
  const int bx = blockIdx.x;
  const int bio = blockIdx.y;
  const u16* inT = inT0 + (size_t)bio * SE_INPT;
  u16* outA = outA0 + (size_t)bio * SE_H;
  const int rq = (bx & 7) * 8 + ((bx >> 3) & 7); // row-quad 0..63, XCD-banded
  const int ph = bx >> 6;                        // px quarter 0..3
  const int row0 = rq * 4, p0 = ph * 64;
  const int wv = tid >> 6, ln = tid & 63, l15 = ln & 15, l4 = ln >> 4;
  f32x4 acc[4][2] = {};

  for (int s = 0; s < 4; s++){
    for (int i = tid; i < 1584; i += 256){
      int rr = i / 264, q = i - rr * 264;
      int pxi = q >> 2, cq = q & 3;
      const u16* src = inT + ((size_t)s * 66564 + (size_t)(row0 + rr) * 258 + (p0 + pxi)) * 32 + cq * 8;
      ((uint4*)inL)[(rr * 66 + pxi) * 4 + (cq ^ ((pxi >> 1) & 3))] = *(const uint4*)src;
    }
    __syncthreads();
    #pragma unroll
    for (int ky = 0; ky < 3; ky++){
      #pragma unroll
      for (int kx = 0; kx < 3; kx++){
        const int tap = ky * 3 + kx;
        bf16x8 bv[2];
        #pragma unroll
        for (int j = 0; j < 2; j++){
          uint4 u = *(const uint4*)(wt + (size_t)(j * 16 + l15) * 1160 + tap * 128 + s * 32 + l4 * 8);
          bv[j] = __builtin_bit_cast(bf16x8, u);
        }
        #pragma unroll
        for (int t = 0; t < 4; t++){
          const int pxL = t * 16 + l15 + kx;
          uint4 uai = ((const uint4*)inL)[((wv + ky) * 66 + pxL) * 4 + (l4 ^ ((pxL >> 1) & 3))];
          bf16x8 av = __builtin_bit_cast(bf16x8, uai);
          #pragma unroll
          for (int j = 0; j < 2; j++)
            acc[t][j] = __builtin_amdgcn_mfma_f32_16x16x32_bf16(av, bv[j], acc[t][j], 0, 0, 0);
        }
      }
    }
    __syncthreads();
  }
  const int row = row0 + wv;
  #pragma unroll
  for (int t = 0; t < 4; t++){
    const int pxb = p0 + t * 16 + l4 * 4;
    #pragma unroll
    for (int j = 0; j < 2; j++){
      const int co = j * 16 + l15;
      const float bs = bias[co];
      #pragma unroll
      for (int r = 0; r < 4; r++){
        const int px = pxb + r;
        float v = lrelu(acc[t][j][r] + bs);
        outA[(size_t)((row + 1) * HP + px + 1) * 32 + co] = f2bf(v);
      }
    }
  }
}

// ---------------- 32-cin convs (conv1/conv2/convf), LDS-staged + XOR bank swizzle ------------
// MODE 0: bias+lrelu -> halo outH (t1). MODE 1: +resid, lrelu -> halo outH (fea) AND fp32 out feats.
// MODE 2: flows (co 0,1) + sigmoid mask (co 2) -> fp32 out.
template<int NT, int MODE>
__global__ __launch_bounds__(256) void k_conv32(const u16* __restrict__ inT0, const u16* __restrict__ wt,
    const float* __restrict__ bias, u16* __restrict__ outH0, float* __restrict__ outF,
    const u16* __restrict__ resid0){
  __shared__ __align__(16) u16 inL[12672];       // [6][66][32]
  const int tid = threadIdx.x;
  const int bx = blockIdx.x;
  const int bio = blockIdx.y;
  const u16* inT = inT0 + (size_t)bio * SE_H;
  const int rq = (bx & 7) * 8 + ((bx >> 3) & 7);
  const int ph = bx >> 6;
  const int row0 = rq * 4, p0 = ph * 64;
  const int wv = tid >> 6, ln = tid & 63, l15 = ln & 15, l4 = ln >> 4;

  for (int i = tid; i < 1584; i += 256){
    int rr = i / 264, q = i - rr * 264;
    int pxi = q >> 2, cq = q & 3;
    const u16* src = inT + ((size_t)(row0 + rr) * 258 + (p0 + pxi)) * 32 + cq * 8;
    ((uint4*)inL)[(rr * 66 + pxi) * 4 + (cq ^ ((pxi >> 1) & 3))] = *(const uint4*)src;
  }
  __syncthreads();

  f32x4 acc[4][NT] = {};
  #pragma unroll
  for (int ky = 0; ky < 3; ky++){
    #pragma unroll
    for (int kx = 0; kx < 3; kx++){
      const int tap = ky * 3 + kx;
      bf16x8 bv[NT];
      #pragma unroll
      for (int j = 0; j < NT; j++){
        uint4 u = *(const uint4*)(wt + (size_t)(j * 16 + l15) * 296 + tap * 32 + l4 * 8);
        bv[j] = __builtin_bit_cast(bf16x8, u);
      }
      #pragma unroll
      for (int t = 0; t < 4; t++){
        const int pxL = t * 16 + l15 + kx;
        uint4 uai = ((const uint4*)inL)[((wv + ky) * 66 + pxL) * 4 + (l4 ^ ((pxL >> 1) & 3))];
        bf16x8 av = __builtin_bit_cast(bf16x8, uai);
        #pragma unroll
        for (int j = 0; j < NT; j++)
          acc[t][j] = __builtin_amdgcn_mfma_f32_16x16x32_bf16(av, bv[j], acc[t][j], 0, 0, 0);
      }
    }
  }
  const int row = row0 + wv;
  #pragma unroll
  for (int t = 0; t < 4; t++){
    const int pxb = p0 + t * 16 + l4 * 4;
    #pragma unroll
    for (int j = 0; j < NT; j++){
      const int co = j * 16 + l15;
      float bs;
      if constexpr (MODE == 2) bs = (co < 3) ? bias[co] : 0.f;
      else bs = bias[co];
      #pragma unroll
      for (int r = 0; r < 4; r++){
        const int px = pxb + r;
        float v = acc[t][j][r] + bs;
        if constexpr (MODE == 0){
          v = lrelu(v);
          outH0[(size_t)bio * SE_H + (size_t)((row + 1) * HP + px + 1) * 32 + co] = f2bf(v);
        } else if constexpr (MODE == 1){
          float hres = bf2f(resid0[(size_t)bio * SE_H + (size_t)((row + 1) * HP + px + 1) * 32 + co]);
          v = lrelu(v + hres);
          outH0[(size_t)bio * SE_H + (size_t)((row + 1) * HP + px + 1) * 32 + co] = f2bf(v); // feaT
          outF[786432 + ((size_t)(bio * 32 + co)) * 65536 + (size_t)row * 256 + px] = v;     // feats
        } else {
          if (co < 2)
            outF[((size_t)(bio * 2 + co)) * 65536 + (size_t)row * 256 + px] = v;             // flows
          else if (co == 2){
            float s = 1.f / (1.f + __expf(-v));
            outF[524288 + (size_t)bio * 65536 + (size_t)row * 256 + px] = s;                 // mask
          }
        }
      }
    }
  }
}

extern "C" void kernel_launch(void* const* d_in, const int* in_sizes, int n_in,
                              void* d_out, int out_size, void* d_ws, size_t ws_size,
                              hipStream_t stream){
  float* out = (float*)d_out;

  // ---- runtime interface verification (kept from R6; encodes any mismatch into out[0]) ----
  static const int exp_sizes[12] = {8388608, 8388608, 131072, 2097152,
                                    33120, 32, 9216, 32, 9216, 32, 864, 3};
  float sent = 0.f;
  if (n_in != 12) sent = 1.0e6f;
  else if (out_size != 9175040) sent = 2.0e6f;
  else {
    for (int i = 0; i < 12; i++)
      if (in_sizes[i] != exp_sizes[i]){ sent = 3.0e6f * (1.0f + 0.01f * i); break; }
    if (sent == 0.f && ws_size < WS_NEED)
      sent = 16.0f * (float)(ws_size >> 20);
  }
  if (sent != 0.f){
    hipLaunchKernelGGL(k_sent, dim3(1), dim3(64), 0, stream, out, sent);
    return;
  }

  const float* xref  = (const float*)d_in[0];
  const float* xnb   = (const float*)d_in[1];
  const float* bflow = (const float*)d_in[2];
  const float* bfeat = (const float*)d_in[3];
  const float* w0 = (const float*)d_in[4];
  const float* b0 = (const float*)d_in[5];
  const float* w1 = (const float*)d_in[6];
  const float* b1 = (const float*)d_in[7];
  const float* w2 = (const float*)d_in[8];
  const float* b2 = (const float*)d_in[9];
  const float* wf = (const float*)d_in[10];
  const float* bf = (const float*)d_in[11];
  char* ws = (char*)d_ws;
  u16* wse   = (u16*)d_ws;
  u16* inpT  = (u16*)(ws + OFF_INPT);
  u16* hT    = (u16*)(ws + OFF_HT);
  u16* t1T   = (u16*)(ws + OFF_T1);
  u16* feaT  = (u16*)(ws + OFF_FEA);
  u16* xrefT = (u16*)(ws + OFF_XREFT);
  u16* xnbT  = (u16*)(ws + OFF_XNBT);

  hipLaunchKernelGGL(k_prep, dim3(2679, 4), dim3(256), 0, stream,
                     xref, xnb, bflow, bfeat, w0, w1, w2, wf, ws);
  hipLaunchKernelGGL(k_corr_mfma, dim3(1024, 4), dim3(256), 0, stream, xrefT, xnbT, ws);
  hipLaunchKernelGGL(k_conv0, dim3(256, 4), dim3(256), 0, stream, inpT, wse + E_WT0, b0, hT);
  hipLaunchKernelGGL((k_conv32<2, 0>), dim3(256, 4), dim3(256), 0, stream,
                     hT, wse + E_WT1, b1, t1T, (float*)nullptr, (const u16*)nullptr);
  hipLaunchKernelGGL((k_conv32<2, 1>), dim3(256, 4), dim3(256), 0, stream,
                     t1T, wse + E_WT2, b2, feaT, out, hT);
  hipLaunchKernelGGL((k_conv32<1, 2>), dim3(256, 4), dim3(256), 0, stream,
                     feaT, wse + E_WTF, bf, (u16*)nullptr, out, (const u16*)nullptr);
}

// Round 13
// 280.786 us; speedup vs baseline: 1.0053x; 1.0053x over previous
//
#include <hip/hip_runtime.h>

typedef unsigned short u16;
typedef unsigned int u32;
typedef __bf16 bf16x8 __attribute__((ext_vector_type(8)));
typedef float f32x4 __attribute__((ext_vector_type(4)));

#define HP 258
// weight-table element offsets within ws (u16 units)
#define E_WT0 0
#define E_WT1 37120
#define E_WT2 46592
#define E_WTF 56064
// ---- per-batch strided layout: all 4 batches resident simultaneously ----
// 258*258 = 66564 pixels. inpT is CHUNK-MAJOR [4 ch-chunks][66564 px][32 ch] bf16.
#define C_CH      4260096ull             // one chunk = 66564*32*2 B
#define OFF_INPT  131072ull
#define S_INPT    17040384ull            // 4*C_CH
#define OFF_HT    68292608ull            // OFF_INPT + 4*S_INPT
#define S_H       4260096ull             // 66564*32*2
#define OFF_T1    85332992ull            // OFF_HT + 4*S_H
#define OFF_FEA   102373376ull           // OFF_T1 + 4*S_H
#define OFF_XREFT 119413760ull           // OFF_FEA + 4*S_H
#define S_XREF    4194304ull             // 256*256*32*2
#define OFF_XNBT  136190976ull           // OFF_XREFT + 4*S_XREF
#define S_XNB     4595712ull             // 264*272*32*2
#define WS_NEED   154573824ull           // OFF_XNBT + 4*S_XNB  (ws is 256 MiB per R2 fill evidence)
// u16-element strides
#define SE_INPT 8520192u
#define SE_H    2130048u
#define SE_XREF 2097152u
#define SE_XNB  2297856u

__device__ __forceinline__ float bf2f(u16 u){ u32 x = ((u32)u) << 16; return __builtin_bit_cast(float, x); }
__device__ __forceinline__ u16 f2bf(float f){
  u32 x = __builtin_bit_cast(u32, f);
  return (u16)((x + 0x7fffu + ((x >> 16) & 1u)) >> 16);   // RNE
}
__device__ __forceinline__ u32 pack2(float a, float b){ return (u32)f2bf(a) | ((u32)f2bf(b) << 16); }
__device__ __forceinline__ float lrelu(float x){ return x >= 0.f ? x : 0.1f * x; }

__global__ void k_sent(float* __restrict__ out, float val){
  if (threadIdx.x == 0 && blockIdx.x == 0) out[0] = val;
}

// ---------------- fused prep: xpose | up | halo | nb-zero | wprep ----------------------------
// R19: xpose role vectorized — thread = 4 px x 8 ch via 8 x float4 loads (128 B in flight,
// 4x R18's scalar-dword depth). Wave = 64 px of one row; nb pad handled by zero-fill role.
// R20 FIX: pad full-row index was r8+252 (clobbered DATA rows 256..259 = image rows 252..255,
// raced with xpose, left pad rows 260..263 garbage -> absmax 0.16). Correct: r8+256.
// Block ranges (uniform per block):
//   [0,256)     xpose ref: wave wvi = bxx*4+wv; row = wvi>>2, px base (wvi&3)*64
//   [256,512)   xpose nb data rows: hp = 4 + (wvi>>2), pt base 4 + (wvi&3)*64
//   [512,768)   up: 1 row per block, thread = 1 px, all 34 ch
//   [768,1029)  halo-ring zeroing
//   [1029,1127) xnbT pad zero-fill (8 full rows {0..3,260..263} + 16 edge cols x 256 rows)
//   [1127,1143) wprep (bio==0 only), grid-stride
__global__ __launch_bounds__(256) void k_prep(const float* __restrict__ xref,
    const float* __restrict__ xnb, const float* __restrict__ bflow,
    const float* __restrict__ bfeat, const float* __restrict__ w0,
    const float* __restrict__ w1, const float* __restrict__ w2,
    const float* __restrict__ wf, char* __restrict__ ws){
  const int tid = threadIdx.x;
  const int bxx = blockIdx.x;
  const int bio = blockIdx.y;

  if (bxx < 512){
    // ---- xpose: [c][h][w] fp32 -> [h][w][c] bf16; thread = 4 px x 8 ch (float4 loads) ----
    const bool isRef = bxx < 256;
    const int wvi = (isRef ? bxx : bxx - 256) * 4 + (tid >> 6);
    const int l = tid & 63;
    const int cq = l & 3, c0 = cq * 8, pg = l >> 2;
    const int px0 = (wvi & 3) * 64 + pg * 4;       // 0..252, 16 B aligned
    const int srow = wvi >> 2;                     // 0..255 (ref row / nb image row)
    const float* srcp = (isRef ? xref : xnb)
                      + ((size_t)(bio * 32 + c0)) * 65536 + (size_t)srow * 256 + px0;
    float4 v4[8];
    #pragma unroll
    for (int k = 0; k < 8; k++) v4[k] = *(const float4*)(srcp + (size_t)k * 65536);
    u16* dstp;
    if (isRef)
      dstp = (u16*)(ws + OFF_XREFT) + (size_t)bio * SE_XREF + ((size_t)srow * 256 + px0) * 32 + c0;
    else
      dstp = (u16*)(ws + OFF_XNBT) + (size_t)bio * SE_XNB
           + ((size_t)(srow + 4) * 272 + (px0 + 4)) * 32 + c0;
    #pragma unroll
    for (int p = 0; p < 4; p++){
      u32 pk[4];
      #pragma unroll
      for (int j = 0; j < 4; j++)
        pk[j] = pack2(((const float*)&v4[2 * j])[p], ((const float*)&v4[2 * j + 1])[p]);
      *(uint4*)(dstp + p * 32) = *(uint4*)pk;
    }
  } else if (bxx < 768){
    // ---- bilinear 2x upsample (ch 0..33) + zero tail ----
    const int ubx = bxx - 512;
    const int w = tid;
    const int h = (ubx & 7) * 32 + (ubx >> 3);   // XCD swizzle
    int y0 = (h >> 1) - 1 + (h & 1);
    const float fy = (h & 1) ? 0.25f : 0.75f;
    const int y0o = (y0 < 0 ? 0 : y0) * 128;
    const int y1o = ((y0 + 1) > 127 ? 127 : (y0 + 1)) * 128;
    int x0 = (w >> 1) - 1 + (w & 1);
    const float fx = (w & 1) ? 0.25f : 0.75f;
    const int x0c = x0 < 0 ? 0 : x0;
    const int x1c = (x0 + 1) > 127 ? 127 : (x0 + 1);
    char* pxb = ws + OFF_INPT + (size_t)bio * S_INPT + ((size_t)(h + 1) * 258 + (w + 1)) * 64;
    u32 pk[16];
    #pragma unroll
    for (int d = 0; d < 16; d++){
      float vv[2];
      #pragma unroll
      for (int e = 0; e < 2; e++){
        const float* pl = bfeat + ((size_t)(bio * 32 + 2 * d + e)) * 16384;
        float v00 = pl[y0o + x0c], v01 = pl[y0o + x1c];
        float v10 = pl[y1o + x0c], v11 = pl[y1o + x1c];
        float r0 = v00 + fx * (v01 - v00);
        float r1 = v10 + fx * (v11 - v10);
        vv[e] = r0 + fy * (r1 - r0);
      }
      pk[d] = pack2(vv[0], vv[1]);
    }
    uint4* dst0 = (uint4*)pxb;
    #pragma unroll
    for (int q = 0; q < 4; q++) dst0[q] = ((uint4*)pk)[q];
    float fv[2];
    #pragma unroll
    for (int e = 0; e < 2; e++){
      const float* pl = bflow + ((size_t)(bio * 2 + e)) * 16384;
      float v00 = pl[y0o + x0c], v01 = pl[y0o + x1c];
      float v10 = pl[y1o + x0c], v11 = pl[y1o + x1c];
      float r0 = v00 + fx * (v01 - v00);
      float r1 = v10 + fx * (v11 - v10);
      fv[e] = (r0 + fy * (r1 - r0)) * 2.f;
    }
    *(u32*)(pxb + C_CH) = pack2(fv[0], fv[1]);
    *(u16*)(pxb + 3 * C_CH + 38) = 0;
    #pragma unroll
    for (int k2 = 0; k2 < 6; k2++) *(u32*)(pxb + 3 * C_CH + 40 + 4 * k2) = 0;
  } else if (bxx < 1029){
    // ---- halo-ring zeroing ----
    int idx = (bxx - 768) * 256 + tid;
    if (idx >= 258 * 258) return;
    int y = idx / 258;
    int x = idx - y * 258;
    if (y != 0 && y != 257 && x != 0 && x != 257) return;
    uint4 z = make_uint4(0u, 0u, 0u, 0u);
    size_t pix = (size_t)idx;
    #pragma unroll
    for (int s = 0; s < 4; s++){
      uint4* q0 = (uint4*)(ws + OFF_INPT + (size_t)bio * S_INPT + (size_t)s * C_CH + pix * 64);
      #pragma unroll
      for (int k = 0; k < 4; k++) q0[k] = z;
    }
    uint4* q1 = (uint4*)(ws + OFF_HT  + (size_t)bio * S_H + pix * 64);
    uint4* q2 = (uint4*)(ws + OFF_T1  + (size_t)bio * S_H + pix * 64);
    uint4* q3 = (uint4*)(ws + OFF_FEA + (size_t)bio * S_H + pix * 64);
    #pragma unroll
    for (int k = 0; k < 4; k++){ q1[k] = z; q2[k] = z; q3[k] = z; }
  } else if (bxx < 1127){
    // ---- xnbT pad zero-fill: rows hp {0..3,260..263} full; pt {0..3,260..271} for hp 4..259 ----
    int unit = (bxx - 1029) * 256 + tid;     // 0..25087, exact (98*256)
    int e = unit >> 2, q = unit & 3;
    int hp, pt;
    if (e < 2176){ int r8 = e / 272; pt = e - r8 * 272; hp = (r8 < 4) ? r8 : r8 + 256; }
    else { int e2 = e - 2176; hp = 4 + (e2 >> 4); int i16 = e2 & 15; pt = (i16 < 4) ? i16 : i16 + 256; }
    uint4 z = make_uint4(0u, 0u, 0u, 0u);
    *(uint4*)(ws + OFF_XNBT + (size_t)bio * S_XNB + ((size_t)hp * 272 + pt) * 64 + q * 16) = z;
  } else {
    // ---- wprep (batch-independent; bio 0 only) ----
    if (bio != 0) return;
    u16* wse = (u16*)ws;
    for (int idx = (bxx - 1127) * 256 + tid; idx < 60800; idx += 4096){
      float v = 0.f;
      if (idx < 37120){                       // Wt0: 32 rows x 1160 (K=9*128=1152 used)
        int co = idx / 1160, kk = idx % 1160;
        if (kk < 1152){
          int tap = kk >> 7, c = kk & 127;
          if (c < 115){
            int oc = (c < 34) ? (81 + c) : (c - 34);
            v = w0[(co * 115 + oc) * 9 + tap];
          }
        }
      } else if (idx < 46592){                // Wt1: 32 x 296 (K=9*32=288)
        int r = idx - 37120; int co = r / 296, kk = r % 296;
        if (kk < 288){ int tap = kk >> 5, c = kk & 31; v = w1[(co * 32 + c) * 9 + tap]; }
      } else if (idx < 56064){                // Wt2
        int r = idx - 46592; int co = r / 296, kk = r % 296;
        if (kk < 288){ int tap = kk >> 5, c = kk & 31; v = w2[(co * 32 + c) * 9 + tap]; }
      } else {                                // Wtf: 16 x 296, rows 3..15 zero
        int r = idx - 56064; int co = r / 296, kk = r % 296;
        if (kk < 288 && co < 3){ int tap = kk >> 5, c = kk & 31; v = wf[(co * 32 + c) * 9 + tap]; }
      }
      wse[idx] = f2bf(v);
    }
  }
}

// ---------------- MFMA correlation: D[m][n] = sum_c ref[c][w0+m] * nb[c][ih][w0+n-4] ----------
// Per wave: 16 px, all 9 dy x 9 dx. Epilogue: predicated 2B stores into chunk-major inpT.
__global__ __launch_bounds__(256) void k_corr_mfma(const u16* __restrict__ xrefT0,
    const u16* __restrict__ xnbT0, char* __restrict__ ws){
  const int tid = threadIdx.x;
  const int wv = tid >> 6, l = tid & 63;
  const int bx = blockIdx.x;
  const int bio = blockIdx.y;
  const u16* xrefT = xrefT0 + (size_t)bio * SE_XREF;
  const u16* xnbT  = xnbT0  + (size_t)bio * SE_XNB;
  const int r = bx & 255, sub = bx >> 8;
  const int h = (r & 7) * 32 + (r >> 3);     // XCD swizzle: nbT row reuse stays on-XCD
  const int w0 = (sub * 4 + wv) * 16;
  const int m16 = l & 15, g = l >> 4;

  uint4 ua = *(const uint4*)(xrefT + ((size_t)h * 256 + w0 + m16) * 32 + g * 8);
  bf16x8 av = __builtin_bit_cast(bf16x8, ua);

  size_t bOff = ((size_t)h * 272 + w0 + m16) * 32 + g * 8;
  char* ob = ws + OFF_INPT + (size_t)bio * S_INPT
             + ((size_t)(h + 1) * 258 + (w0 + 1) + g * 4) * 64;
  const f32x4 z = {0.f, 0.f, 0.f, 0.f};
  #pragma unroll
  for (int dy = 0; dy < 9; dy++){
    uint4 ub0 = *(const uint4*)(xnbT + bOff);
    uint4 ub1 = *(const uint4*)(xnbT + bOff + 512);
    bOff += 8704;                            // next padded row (272*32)
    f32x4 d0 = __builtin_amdgcn_mfma_f32_16x16x32_bf16(av, __builtin_bit_cast(bf16x8, ub0), z, 0, 0, 0);
    f32x4 d1 = __builtin_amdgcn_mfma_f32_16x16x32_bf16(av, __builtin_bit_cast(bf16x8, ub1), z, 0, 0, 0);
    #pragma unroll
    for (int j = 0; j < 4; j++){
      int dxa = m16 - g * 4 - j;             // frag0: dx = n - m
      int dxb = dxa + 16;                    // frag1: dx = n + 16 - m
      bool va = (unsigned)dxa <= 8u;
      bool vb = (unsigned)dxb <= 8u;
      if (va | vb){
        float val = va ? d0[j] : d1[j];
        int dx = va ? dxa : dxb;
        float f = lrelu(val * 0.03125f);
        int c = 34 + dy * 9 + dx;            // chunk-major channel
        *(u16*)(ob + j * 64 + (size_t)(c >> 5) * C_CH + (c & 31) * 2) = f2bf(f);
      }
    }
  }
}

// ---------------- conv0: 128->32, LDS-staged input (s-chunked), weights from global(L2) ------
// R17 geometry (4 rows x 64 px, 25.3 KB LDS) + R18 XOR bank swizzle:
// 16B unit (pxi,cq) stored at unit index (row*66+pxi)*4 + (cq ^ ((pxi>>1)&3)) -> 16-lane
// ds_read_b128 hits 8 distinct bank-bases (2 lanes/bank = free) vs 2 (8-way) unswizzled.
__global__ __launch_bounds__(256) void k_conv0(const u16* __restrict__ inT0, const u16* __restrict__ wt,
    const float* __restrict__ bias, u16* __restrict__ outA0){
  __shared__ __align__(16) u16 inL[12672];       // [6][66][32]
  const int tid = threadIdx.x;
  const int bx = blockIdx.x;
  const int bio = blockIdx.y;
  const u16* inT = inT0 + (size_t)bio * SE_INPT;
  u16* outA = outA0 + (size_t)bio * SE_H;
  const int rq = (bx & 7) * 8 + ((bx >> 3) & 7); // row-quad 0..63, XCD-banded
  const int ph = bx >> 6;                        // px quarter 0..3
  const int row0 = rq * 4, p0 = ph * 64;
  const int wv = tid >> 6, ln = tid & 63, l15 = ln & 15, l4 = ln >> 4;
  f32x4 acc[4][2] = {};

  for (int s = 0; s < 4; s++){
    for (int i = tid; i < 1584; i += 256){
      int rr = i / 264, q = i - rr * 264;
      int pxi = q >> 2, cq = q & 3;
      const u16* src = inT + ((size_t)s * 66564 + (size_t)(row0 + rr) * 258 + (p0 + pxi)) * 32 + cq * 8;
      ((uint4*)inL)[(rr * 66 + pxi) * 4 + (cq ^ ((pxi >> 1) & 3))] = *(const uint4*)src;
    }
    __syncthreads();
    #pragma unroll
    for (int ky = 0; ky < 3; ky++){
      #pragma unroll
      for (int kx = 0; kx < 3; kx++){
        const int tap = ky * 3 + kx;
        bf16x8 bv[2];
        #pragma unroll
        for (int j = 0; j < 2; j++){
          uint4 u = *(const uint4*)(wt + (size_t)(j * 16 + l15) * 1160 + tap * 128 + s * 32 + l4 * 8);
          bv[j] = __builtin_bit_cast(bf16x8, u);
        }
        #pragma unroll
        for (int t = 0; t < 4; t++){
          const int pxL = t * 16 + l15 + kx;
          uint4 uai = ((const uint4*)inL)[((wv + ky) * 66 + pxL) * 4 + (l4 ^ ((pxL >> 1) & 3))];
          bf16x8 av = __builtin_bit_cast(bf16x8, uai);
          #pragma unroll
          for (int j = 0; j < 2; j++)
            acc[t][j] = __builtin_amdgcn_mfma_f32_16x16x32_bf16(av, bv[j], acc[t][j], 0, 0, 0);
        }
      }
    }
    __syncthreads();
  }
  const int row = row0 + wv;
  #pragma unroll
  for (int t = 0; t < 4; t++){
    const int pxb = p0 + t * 16 + l4 * 4;
    #pragma unroll
    for (int j = 0; j < 2; j++){
      const int co = j * 16 + l15;
      const float bs = bias[co];
      #pragma unroll
      for (int r = 0; r < 4; r++){
        const int px = pxb + r;
        float v = lrelu(acc[t][j][r] + bs);
        outA[(size_t)((row + 1) * HP + px + 1) * 32 + co] = f2bf(v);
      }
    }
  }
}

// ---------------- 32-cin convs (conv1/conv2/convf), LDS-staged + XOR bank swizzle ------------
// MODE 0: bias+lrelu -> halo outH (t1). MODE 1: +resid, lrelu -> halo outH (fea) AND fp32 out feats.
// MODE 2: flows (co 0,1) + sigmoid mask (co 2) -> fp32 out.
template<int NT, int MODE>
__global__ __launch_bounds__(256) void k_conv32(const u16* __restrict__ inT0, const u16* __restrict__ wt,
    const float* __restrict__ bias, u16* __restrict__ outH0, float* __restrict__ outF,
    const u16* __restrict__ resid0){
  __shared__ __align__(16) u16 inL[12672];       // [6][66][32]
  const int tid = threadIdx.x;
  const int bx = blockIdx.x;
  const int bio = blockIdx.y;
  const u16* inT = inT0 + (size_t)bio * SE_H;
  const int rq = (bx & 7) * 8 + ((bx >> 3) & 7);
  const int ph = bx >> 6;
  const int row0 = rq * 4, p0 = ph * 64;
  const int wv = tid >> 6, ln = tid & 63, l15 = ln & 15, l4 = ln >> 4;

  for (int i = tid; i < 1584; i += 256){
    int rr = i / 264, q = i - rr * 264;
    int pxi = q >> 2, cq = q & 3;
    const u16* src = inT + ((size_t)(row0 + rr) * 258 + (p0 + pxi)) * 32 + cq * 8;
    ((uint4*)inL)[(rr * 66 + pxi) * 4 + (cq ^ ((pxi >> 1) & 3))] = *(const uint4*)src;
  }
  __syncthreads();

  f32x4 acc[4][NT] = {};
  #pragma unroll
  for (int ky = 0; ky < 3; ky++){
    #pragma unroll
    for (int kx = 0; kx < 3; kx++){
      const int tap = ky * 3 + kx;
      bf16x8 bv[NT];
      #pragma unroll
      for (int j = 0; j < NT; j++){
        uint4 u = *(const uint4*)(wt + (size_t)(j * 16 + l15) * 296 + tap * 32 + l4 * 8);
        bv[j] = __builtin_bit_cast(bf16x8, u);
      }
      #pragma unroll
      for (int t = 0; t < 4; t++){
        const int pxL = t * 16 + l15 + kx;
        uint4 uai = ((const uint4*)inL)[((wv + ky) * 66 + pxL) * 4 + (l4 ^ ((pxL >> 1) & 3))];
        bf16x8 av = __builtin_bit_cast(bf16x8, uai);
        #pragma unroll
        for (int j = 0; j < NT; j++)
          acc[t][j] = __builtin_amdgcn_mfma_f32_16x16x32_bf16(av, bv[j], acc[t][j], 0, 0, 0);
      }
    }
  }
  const int row = row0 + wv;
  #pragma unroll
  for (int t = 0; t < 4; t++){
    const int pxb = p0 + t * 16 + l4 * 4;
    #pragma unroll
    for (int j = 0; j < NT; j++){
      const int co = j * 16 + l15;
      float bs;
      if constexpr (MODE == 2) bs = (co < 3) ? bias[co] : 0.f;
      else bs = bias[co];
      #pragma unroll
      for (int r = 0; r < 4; r++){
        const int px = pxb + r;
        float v = acc[t][j][r] + bs;
        if constexpr (MODE == 0){
          v = lrelu(v);
          outH0[(size_t)bio * SE_H + (size_t)((row + 1) * HP + px + 1) * 32 + co] = f2bf(v);
        } else if constexpr (MODE == 1){
          float hres = bf2f(resid0[(size_t)bio * SE_H + (size_t)((row + 1) * HP + px + 1) * 32 + co]);
          v = lrelu(v + hres);
          outH0[(size_t)bio * SE_H + (size_t)((row + 1) * HP + px + 1) * 32 + co] = f2bf(v); // feaT
          outF[786432 + ((size_t)(bio * 32 + co)) * 65536 + (size_t)row * 256 + px] = v;     // feats
        } else {
          if (co < 2)
            outF[((size_t)(bio * 2 + co)) * 65536 + (size_t)row * 256 + px] = v;             // flows
          else if (co == 2){
            float s = 1.f / (1.f + __expf(-v));
            outF[524288 + (size_t)bio * 65536 + (size_t)row * 256 + px] = s;                 // mask
          }
        }
      }
    }
  }
}

extern "C" void kernel_launch(void* const* d_in, const int* in_sizes, int n_in,
                              void* d_out, int out_size, void* d_ws, size_t ws_size,
                              hipStream_t stream){
  float* out = (float*)d_out;

  // ---- runtime interface verification (kept from R6; encodes any mismatch into out[0]) ----
  static const int exp_sizes[12] = {8388608, 8388608, 131072, 2097152,
                                    33120, 32, 9216, 32, 9216, 32, 864, 3};
  float sent = 0.f;
  if (n_in != 12) sent = 1.0e6f;
  else if (out_size != 9175040) sent = 2.0e6f;
  else {
    for (int i = 0; i < 12; i++)
      if (in_sizes[i] != exp_sizes[i]){ sent = 3.0e6f * (1.0f + 0.01f * i); break; }
    if (sent == 0.f && ws_size < WS_NEED)
      sent = 16.0f * (float)(ws_size >> 20);
  }
  if (sent != 0.f){
    hipLaunchKernelGGL(k_sent, dim3(1), dim3(64), 0, stream, out, sent);
    return;
  }

  const float* xref  = (const float*)d_in[0];
  const float* xnb   = (const float*)d_in[1];
  const float* bflow = (const float*)d_in[2];
  const float* bfeat = (const float*)d_in[3];
  const float* w0 = (const float*)d_in[4];
  const float* b0 = (const float*)d_in[5];
  const float* w1 = (const float*)d_in[6];
  const float* b1 = (const float*)d_in[7];
  const float* w2 = (const float*)d_in[8];
  const float* b2 = (const float*)d_in[9];
  const float* wf = (const float*)d_in[10];
  const float* bf = (const float*)d_in[11];
  char* ws = (char*)d_ws;
  u16* wse   = (u16*)d_ws;
  u16* inpT  = (u16*)(ws + OFF_INPT);
  u16* hT    = (u16*)(ws + OFF_HT);
  u16* t1T   = (u16*)(ws + OFF_T1);
  u16* feaT  = (u16*)(ws + OFF_FEA);
  u16* xrefT = (u16*)(ws + OFF_XREFT);
  u16* xnbT  = (u16*)(ws + OFF_XNBT);

  hipLaunchKernelGGL(k_prep, dim3(1143, 4), dim3(256), 0, stream,
                     xref, xnb, bflow, bfeat, w0, w1, w2, wf, ws);
  hipLaunchKernelGGL(k_corr_mfma, dim3(1024, 4), dim3(256), 0, stream, xrefT, xnbT, ws);
  hipLaunchKernelGGL(k_conv0, dim3(256, 4), dim3(256), 0, stream, inpT, wse + E_WT0, b0, hT);
  hipLaunchKernelGGL((k_conv32<2, 0>), dim3(256, 4), dim3(256), 0, stream,
                     hT, wse + E_WT1, b1, t1T, (float*)nullptr, (const u16*)nullptr);
  hipLaunchKernelGGL((k_conv32<2, 1>), dim3(256, 4), dim3(256), 0, stream,
                     t1T, wse + E_WT2, b2, feaT, out, hT);
  hipLaunchKernelGGL((k_conv32<1, 2>), dim3(256, 4), dim3(256), 0, stream,
                     feaT, wse + E_WTF, bf, (u16*)nullptr, out, (const u16*)nullptr);
}

// Round 14
// 279.444 us; speedup vs baseline: 1.0101x; 1.0048x over previous
//
#include <hip/hip_runtime.h>

typedef unsigned short u16;
typedef unsigned int u32;
typedef __bf16 bf16x8 __attribute__((ext_vector_type(8)));
typedef float f32x4 __attribute__((ext_vector_type(4)));

#define HP 258
// weight-table element offsets within ws (u16 units)
#define E_WT0 0
#define E_WT1 37120
#define E_WT2 46592
#define E_WTF 56064
// ---- per-batch strided layout: all 4 batches resident simultaneously ----
// 258*258 = 66564 pixels. inpT is CHUNK-MAJOR [4 ch-chunks][66564 px][32 ch] bf16.
#define C_CH      4260096ull             // one chunk = 66564*32*2 B
#define OFF_INPT  131072ull
#define S_INPT    17040384ull            // 4*C_CH
#define OFF_HT    68292608ull            // OFF_INPT + 4*S_INPT
#define S_H       4260096ull             // 66564*32*2
#define OFF_T1    85332992ull            // OFF_HT + 4*S_H
#define OFF_FEA   102373376ull           // OFF_T1 + 4*S_H
#define OFF_XREFT 119413760ull           // OFF_FEA + 4*S_H
#define S_XREF    4194304ull             // 256*256*32*2
#define OFF_XNBT  136190976ull           // OFF_XREFT + 4*S_XREF
#define S_XNB     4595712ull             // 264*272*32*2
#define WS_NEED   154573824ull           // OFF_XNBT + 4*S_XNB  (ws is 256 MiB per R2 fill evidence)
// u16-element strides
#define SE_INPT 8520192u
#define SE_H    2130048u
#define SE_XREF 2097152u
#define SE_XNB  2297856u

__device__ __forceinline__ float bf2f(u16 u){ u32 x = ((u32)u) << 16; return __builtin_bit_cast(float, x); }
__device__ __forceinline__ u16 f2bf(float f){
  u32 x = __builtin_bit_cast(u32, f);
  return (u16)((x + 0x7fffu + ((x >> 16) & 1u)) >> 16);   // RNE
}
__device__ __forceinline__ u32 pack2(float a, float b){ return (u32)f2bf(a) | ((u32)f2bf(b) << 16); }
__device__ __forceinline__ float lrelu(float x){ return x >= 0.f ? x : 0.1f * x; }

__global__ void k_sent(float* __restrict__ out, float val){
  if (threadIdx.x == 0 && blockIdx.x == 0) out[0] = val;
}

// ---------------- fused prep: xpose | up | halo | nb-zero | wprep ----------------------------
// R21: xpose role via global_load_lds (async, no VGPR round-trip). R13 post-mortem: reg-staged
// loads (scalar R16 and float4 R19) both strangled to ~2.2 TB/s by compiler waitcnt/VGPR=36.
// New xpose: block = 1 image row; wave issues 8 back-to-back global_load_lds (ch -> LDS[c][258],
// lane l -> px 4l, 16 B each), barrier, thread = 1 px packs 32 ch -> one 64 B store.
// Block ranges (uniform per block):
//   [0,512)     xpose: bxx<256 ref row bxx; else nb image row bxx-256 (dst row +4, px +4)
//   [512,768)   up: 1 row per block, thread = 1 px, all 34 ch
//   [768,1029)  halo-ring zeroing
//   [1029,1127) xnbT pad zero-fill (8 full rows {0..3,260..263} + 16 edge cols x 256 rows)
//   [1127,1143) wprep (bio==0 only), grid-stride
__global__ __launch_bounds__(256) void k_prep(const float* __restrict__ xref,
    const float* __restrict__ xnb, const float* __restrict__ bflow,
    const float* __restrict__ bfeat, const float* __restrict__ w0,
    const float* __restrict__ w1, const float* __restrict__ w2,
    const float* __restrict__ wf, char* __restrict__ ws){
  __shared__ __align__(16) float xl[32 * 258];   // [ch][px pad->258] fp32, 33 KB
  const int tid = threadIdx.x;
  const int bxx = blockIdx.x;
  const int bio = blockIdx.y;

  if (bxx < 512){
    // ---- xpose: [c][h][w] fp32 -> [h][w][c] bf16 via LDS, async staging ----
    const bool isRef = bxx < 256;
    const int srow = isRef ? bxx : bxx - 256;
    const int wv = tid >> 6, l = tid & 63;
    const float* base = (isRef ? xref : xnb) + ((size_t)bio * 32) * 65536 + (size_t)srow * 256;
    #pragma unroll
    for (int k = 0; k < 8; k++){
      const int c = wv * 8 + k;
      const float* src = base + (size_t)c * 65536 + l * 4;
      __builtin_amdgcn_global_load_lds(
          (const __attribute__((address_space(1))) unsigned int*)src,
          (__attribute__((address_space(3))) unsigned int*)&xl[c * 258], 16, 0, 0);
    }
    __syncthreads();
    u32 pk[16];
    #pragma unroll
    for (int j = 0; j < 16; j++)
      pk[j] = pack2(xl[(2 * j) * 258 + tid], xl[(2 * j + 1) * 258 + tid]);
    u16* dstp;
    if (isRef)
      dstp = (u16*)(ws + OFF_XREFT) + (size_t)bio * SE_XREF + ((size_t)srow * 256 + tid) * 32;
    else
      dstp = (u16*)(ws + OFF_XNBT) + (size_t)bio * SE_XNB
           + ((size_t)(srow + 4) * 272 + (tid + 4)) * 32;
    #pragma unroll
    for (int q = 0; q < 4; q++) ((uint4*)dstp)[q] = ((uint4*)pk)[q];
  } else if (bxx < 768){
    // ---- bilinear 2x upsample (ch 0..33) + zero tail ----
    const int ubx = bxx - 512;
    const int w = tid;
    const int h = (ubx & 7) * 32 + (ubx >> 3);   // XCD swizzle
    int y0 = (h >> 1) - 1 + (h & 1);
    const float fy = (h & 1) ? 0.25f : 0.75f;
    const int y0o = (y0 < 0 ? 0 : y0) * 128;
    const int y1o = ((y0 + 1) > 127 ? 127 : (y0 + 1)) * 128;
    int x0 = (w >> 1) - 1 + (w & 1);
    const float fx = (w & 1) ? 0.25f : 0.75f;
    const int x0c = x0 < 0 ? 0 : x0;
    const int x1c = (x0 + 1) > 127 ? 127 : (x0 + 1);
    char* pxb = ws + OFF_INPT + (size_t)bio * S_INPT + ((size_t)(h + 1) * 258 + (w + 1)) * 64;
    u32 pk[16];
    #pragma unroll
    for (int d = 0; d < 16; d++){
      float vv[2];
      #pragma unroll
      for (int e = 0; e < 2; e++){
        const float* pl = bfeat + ((size_t)(bio * 32 + 2 * d + e)) * 16384;
        float v00 = pl[y0o + x0c], v01 = pl[y0o + x1c];
        float v10 = pl[y1o + x0c], v11 = pl[y1o + x1c];
        float r0 = v00 + fx * (v01 - v00);
        float r1 = v10 + fx * (v11 - v10);
        vv[e] = r0 + fy * (r1 - r0);
      }
      pk[d] = pack2(vv[0], vv[1]);
    }
    uint4* dst0 = (uint4*)pxb;
    #pragma unroll
    for (int q = 0; q < 4; q++) dst0[q] = ((uint4*)pk)[q];
    float fv[2];
    #pragma unroll
    for (int e = 0; e < 2; e++){
      const float* pl = bflow + ((size_t)(bio * 2 + e)) * 16384;
      float v00 = pl[y0o + x0c], v01 = pl[y0o + x1c];
      float v10 = pl[y1o + x0c], v11 = pl[y1o + x1c];
      float r0 = v00 + fx * (v01 - v00);
      float r1 = v10 + fx * (v11 - v10);
      fv[e] = (r0 + fy * (r1 - r0)) * 2.f;
    }
    *(u32*)(pxb + C_CH) = pack2(fv[0], fv[1]);
    *(u16*)(pxb + 3 * C_CH + 38) = 0;
    #pragma unroll
    for (int k2 = 0; k2 < 6; k2++) *(u32*)(pxb + 3 * C_CH + 40 + 4 * k2) = 0;
  } else if (bxx < 1029){
    // ---- halo-ring zeroing ----
    int idx = (bxx - 768) * 256 + tid;
    if (idx >= 258 * 258) return;
    int y = idx / 258;
    int x = idx - y * 258;
    if (y != 0 && y != 257 && x != 0 && x != 257) return;
    uint4 z = make_uint4(0u, 0u, 0u, 0u);
    size_t pix = (size_t)idx;
    #pragma unroll
    for (int s = 0; s < 4; s++){
      uint4* q0 = (uint4*)(ws + OFF_INPT + (size_t)bio * S_INPT + (size_t)s * C_CH + pix * 64);
      #pragma unroll
      for (int k = 0; k < 4; k++) q0[k] = z;
    }
    uint4* q1 = (uint4*)(ws + OFF_HT  + (size_t)bio * S_H + pix * 64);
    uint4* q2 = (uint4*)(ws + OFF_T1  + (size_t)bio * S_H + pix * 64);
    uint4* q3 = (uint4*)(ws + OFF_FEA + (size_t)bio * S_H + pix * 64);
    #pragma unroll
    for (int k = 0; k < 4; k++){ q1[k] = z; q2[k] = z; q3[k] = z; }
  } else if (bxx < 1127){
    // ---- xnbT pad zero-fill: rows hp {0..3,260..263} full; pt {0..3,260..271} for hp 4..259 ----
    int unit = (bxx - 1029) * 256 + tid;     // 0..25087, exact (98*256)
    int e = unit >> 2, q = unit & 3;
    int hp, pt;
    if (e < 2176){ int r8 = e / 272; pt = e - r8 * 272; hp = (r8 < 4) ? r8 : r8 + 256; }
    else { int e2 = e - 2176; hp = 4 + (e2 >> 4); int i16 = e2 & 15; pt = (i16 < 4) ? i16 : i16 + 256; }
    uint4 z = make_uint4(0u, 0u, 0u, 0u);
    *(uint4*)(ws + OFF_XNBT + (size_t)bio * S_XNB + ((size_t)hp * 272 + pt) * 64 + q * 16) = z;
  } else {
    // ---- wprep (batch-independent; bio 0 only) ----
    if (bio != 0) return;
    u16* wse = (u16*)ws;
    for (int idx = (bxx - 1127) * 256 + tid; idx < 60800; idx += 4096){
      float v = 0.f;
      if (idx < 37120){                       // Wt0: 32 rows x 1160 (K=9*128=1152 used)
        int co = idx / 1160, kk = idx % 1160;
        if (kk < 1152){
          int tap = kk >> 7, c = kk & 127;
          if (c < 115){
            int oc = (c < 34) ? (81 + c) : (c - 34);
            v = w0[(co * 115 + oc) * 9 + tap];
          }
        }
      } else if (idx < 46592){                // Wt1: 32 x 296 (K=9*32=288)
        int r = idx - 37120; int co = r / 296, kk = r % 296;
        if (kk < 288){ int tap = kk >> 5, c = kk & 31; v = w1[(co * 32 + c) * 9 + tap]; }
      } else if (idx < 56064){                // Wt2
        int r = idx - 46592; int co = r / 296, kk = r % 296;
        if (kk < 288){ int tap = kk >> 5, c = kk & 31; v = w2[(co * 32 + c) * 9 + tap]; }
      } else {                                // Wtf: 16 x 296, rows 3..15 zero
        int r = idx - 56064; int co = r / 296, kk = r % 296;
        if (kk < 288 && co < 3){ int tap = kk >> 5, c = kk & 31; v = wf[(co * 32 + c) * 9 + tap]; }
      }
      wse[idx] = f2bf(v);
    }
  }
}

// ---------------- MFMA correlation: D[m][n] = sum_c ref[c][w0+m] * nb[c][ih][w0+n-4] ----------
// Per wave: 16 px, all 9 dy x 9 dx. Epilogue: predicated 2B stores into chunk-major inpT.
__global__ __launch_bounds__(256) void k_corr_mfma(const u16* __restrict__ xrefT0,
    const u16* __restrict__ xnbT0, char* __restrict__ ws){
  const int tid = threadIdx.x;
  const int wv = tid >> 6, l = tid & 63;
  const int bx = blockIdx.x;
  const int bio = blockIdx.y;
  const u16* xrefT = xrefT0 + (size_t)bio * SE_XREF;
  const u16* xnbT  = xnbT0  + (size_t)bio * SE_XNB;
  const int r = bx & 255, sub = bx >> 8;
  const int h = (r & 7) * 32 + (r >> 3);     // XCD swizzle: nbT row reuse stays on-XCD
  const int w0 = (sub * 4 + wv) * 16;
  const int m16 = l & 15, g = l >> 4;

  uint4 ua = *(const uint4*)(xrefT + ((size_t)h * 256 + w0 + m16) * 32 + g * 8);
  bf16x8 av = __builtin_bit_cast(bf16x8, ua);

  size_t bOff = ((size_t)h * 272 + w0 + m16) * 32 + g * 8;
  char* ob = ws + OFF_INPT + (size_t)bio * S_INPT
             + ((size_t)(h + 1) * 258 + (w0 + 1) + g * 4) * 64;
  const f32x4 z = {0.f, 0.f, 0.f, 0.f};
  #pragma unroll
  for (int dy = 0; dy < 9; dy++){
    uint4 ub0 = *(const uint4*)(xnbT + bOff);
    uint4 ub1 = *(const uint4*)(xnbT + bOff + 512);
    bOff += 8704;                            // next padded row (272*32)
    f32x4 d0 = __builtin_amdgcn_mfma_f32_16x16x32_bf16(av, __builtin_bit_cast(bf16x8, ub0), z, 0, 0, 0);
    f32x4 d1 = __builtin_amdgcn_mfma_f32_16x16x32_bf16(av, __builtin_bit_cast(bf16x8, ub1), z, 0, 0, 0);
    #pragma unroll
    for (int j = 0; j < 4; j++){
      int dxa = m16 - g * 4 - j;             // frag0: dx = n - m
      int dxb = dxa + 16;                    // frag1: dx = n + 16 - m
      bool va = (unsigned)dxa <= 8u;
      bool vb = (unsigned)dxb <= 8u;
      if (va | vb){
        float val = va ? d0[j] : d1[j];
        int dx = va ? dxa : dxb;
        float f = lrelu(val * 0.03125f);
        int c = 34 + dy * 9 + dx;            // chunk-major channel
        *(u16*)(ob + j * 64 + (size_t)(c >> 5) * C_CH + (c & 31) * 2) = f2bf(f);
      }
    }
  }
}

// ---------------- conv0: 128->32, LDS-staged input (s-chunked), weights from global(L2) ------
// R17 geometry (4 rows x 64 px, 25.3 KB LDS) + R18 XOR bank swizzle:
// 16B unit (pxi,cq) stored at unit index (row*66+pxi)*4 + (cq ^ ((pxi>>1)&3)) -> 16-lane
// ds_read_b128 hits 8 distinct bank-bases (2 lanes/bank = free) vs 2 (8-way) unswizzled.
__global__ __launch_bounds__(256) void k_conv0(const u16* __restrict__ inT0, const u16* __restrict__ wt,
    const float* __restrict__ bias, u16* __restrict__ outA0){
  __shared__ __align__(16) u16 inL[12672];       // [6][66][32]
  const int tid = threadIdx.x;
  const int bx = blockIdx.x;
  const int bio = blockIdx.y;
  const u16* inT = inT0 + (size_t)bio * SE_INPT;
  u16* outA = outA0 + (size_t)bio * SE_H;
  const int rq = (bx & 7) * 8 + ((bx >> 3) & 7); // row-quad 0..63, XCD-banded
  const int ph = bx >> 6;                        // px quarter 0..3
  const int row0 = rq * 4, p0 = ph * 64;
  const int wv = tid >> 6, ln = tid & 63, l15 = ln & 15, l4 = ln >> 4;
  f32x4 acc[4][2] = {};

  for (int s = 0; s < 4; s++){
    for (int i = tid; i < 1584; i += 256){
      int rr = i / 264, q = i - rr * 264;
      int pxi = q >> 2, cq = q & 3;
      const u16* src = inT + ((size_t)s * 66564 + (size_t)(row0 + rr) * 258 + (p0 + pxi)) * 32 + cq * 8;
      ((uint4*)inL)[(rr * 66 + pxi) * 4 + (cq ^ ((pxi >> 1) & 3))] = *(const uint4*)src;
    }
    __syncthreads();
    #pragma unroll
    for (int ky = 0; ky < 3; ky++){
      #pragma unroll
      for (int kx = 0; kx < 3; kx++){
        const int tap = ky * 3 + kx;
        bf16x8 bv[2];
        #pragma unroll
        for (int j = 0; j < 2; j++){
          uint4 u = *(const uint4*)(wt + (size_t)(j * 16 + l15) * 1160 + tap * 128 + s * 32 + l4 * 8);
          bv[j] = __builtin_bit_cast(bf16x8, u);
        }
        #pragma unroll
        for (int t = 0; t < 4; t++){
          const int pxL = t * 16 + l15 + kx;
          uint4 uai = ((const uint4*)inL)[((wv + ky) * 66 + pxL) * 4 + (l4 ^ ((pxL >> 1) & 3))];
          bf16x8 av = __builtin_bit_cast(bf16x8, uai);
          #pragma unroll
          for (int j = 0; j < 2; j++)
            acc[t][j] = __builtin_amdgcn_mfma_f32_16x16x32_bf16(av, bv[j], acc[t][j], 0, 0, 0);
        }
      }
    }
    __syncthreads();
  }
  const int row = row0 + wv;
  #pragma unroll
  for (int t = 0; t < 4; t++){
    const int pxb = p0 + t * 16 + l4 * 4;
    #pragma unroll
    for (int j = 0; j < 2; j++){
      const int co = j * 16 + l15;
      const float bs = bias[co];
      #pragma unroll
      for (int r = 0; r < 4; r++){
        const int px = pxb + r;
        float v = lrelu(acc[t][j][r] + bs);
        outA[(size_t)((row + 1) * HP + px + 1) * 32 + co] = f2bf(v);
      }
    }
  }
}

// ---------------- 32-cin convs (conv1/conv2/convf), LDS-staged + XOR bank swizzle ------------
// MODE 0: bias+lrelu -> halo outH (t1). MODE 1: +resid, lrelu -> halo outH (fea) AND fp32 out feats.
// MODE 2: flows (co 0,1) + sigmoid mask (co 2) -> fp32 out.
template<int NT, int MODE>
__global__ __launch_bounds__(256) void k_conv32(const u16* __restrict__ inT0, const u16* __restrict__ wt,
    const float* __restrict__ bias, u16* __restrict__ outH0, float* __restrict__ outF,
    const u16* __restrict__ resid0){
  __shared__ __align__(16) u16 inL[12672];       // [6][66][32]
  const int tid = threadIdx.x;
  const int bx = blockIdx.x;
  const int bio = blockIdx.y;
  const u16* inT = inT0 + (size_t)bio * SE_H;
  const int rq = (bx & 7) * 8 + ((bx >> 3) & 7);
  const int ph = bx >> 6;
  const int row0 = rq * 4, p0 = ph * 64;
  const int wv = tid >> 6, ln = tid & 63, l15 = ln & 15, l4 = ln >> 4;

  for (int i = tid; i < 1584; i += 256){
    int rr = i / 264, q = i - rr * 264;
    int pxi = q >> 2, cq = q & 3;
    const u16* src = inT + ((size_t)(row0 + rr) * 258 + (p0 + pxi)) * 32 + cq * 8;
    ((uint4*)inL)[(rr * 66 + pxi) * 4 + (cq ^ ((pxi >> 1) & 3))] = *(const uint4*)src;
  }
  __syncthreads();

  f32x4 acc[4][NT] = {};
  #pragma unroll
  for (int ky = 0; ky < 3; ky++){
    #pragma unroll
    for (int kx = 0; kx < 3; kx++){
      const int tap = ky * 3 + kx;
      bf16x8 bv[NT];
      #pragma unroll
      for (int j = 0; j < NT; j++){
        uint4 u = *(const uint4*)(wt + (size_t)(j * 16 + l15) * 296 + tap * 32 + l4 * 8);
        bv[j] = __builtin_bit_cast(bf16x8, u);
      }
      #pragma unroll
      for (int t = 0; t < 4; t++){
        const int pxL = t * 16 + l15 + kx;
        uint4 uai = ((const uint4*)inL)[((wv + ky) * 66 + pxL) * 4 + (l4 ^ ((pxL >> 1) & 3))];
        bf16x8 av = __builtin_bit_cast(bf16x8, uai);
        #pragma unroll
        for (int j = 0; j < NT; j++)
          acc[t][j] = __builtin_amdgcn_mfma_f32_16x16x32_bf16(av, bv[j], acc[t][j], 0, 0, 0);
      }
    }
  }
  const int row = row0 + wv;
  #pragma unroll
  for (int t = 0; t < 4; t++){
    const int pxb = p0 + t * 16 + l4 * 4;
    #pragma unroll
    for (int j = 0; j < NT; j++){
      const int co = j * 16 + l15;
      float bs;
      if constexpr (MODE == 2) bs = (co < 3) ? bias[co] : 0.f;
      else bs = bias[co];
      #pragma unroll
      for (int r = 0; r < 4; r++){
        const int px = pxb + r;
        float v = acc[t][j][r] + bs;
        if constexpr (MODE == 0){
          v = lrelu(v);
          outH0[(size_t)bio * SE_H + (size_t)((row + 1) * HP + px + 1) * 32 + co] = f2bf(v);
        } else if constexpr (MODE == 1){
          float hres = bf2f(resid0[(size_t)bio * SE_H + (size_t)((row + 1) * HP + px + 1) * 32 + co]);
          v = lrelu(v + hres);
          outH0[(size_t)bio * SE_H + (size_t)((row + 1) * HP + px + 1) * 32 + co] = f2bf(v); // feaT
          outF[786432 + ((size_t)(bio * 32 + co)) * 65536 + (size_t)row * 256 + px] = v;     // feats
        } else {
          if (co < 2)
            outF[((size_t)(bio * 2 + co)) * 65536 + (size_t)row * 256 + px] = v;             // flows
          else if (co == 2){
            float s = 1.f / (1.f + __expf(-v));
            outF[524288 + (size_t)bio * 65536 + (size_t)row * 256 + px] = s;                 // mask
          }
        }
      }
    }
  }
}

extern "C" void kernel_launch(void* const* d_in, const int* in_sizes, int n_in,
                              void* d_out, int out_size, void* d_ws, size_t ws_size,
                              hipStream_t stream){
  float* out = (float*)d_out;

  // ---- runtime interface verification (kept from R6; encodes any mismatch into out[0]) ----
  static const int exp_sizes[12] = {8388608, 8388608, 131072, 2097152,
                                    33120, 32, 9216, 32, 9216, 32, 864, 3};
  float sent = 0.f;
  if (n_in != 12) sent = 1.0e6f;
  else if (out_size != 9175040) sent = 2.0e6f;
  else {
    for (int i = 0; i < 12; i++)
      if (in_sizes[i] != exp_sizes[i]){ sent = 3.0e6f * (1.0f + 0.01f * i); break; }
    if (sent == 0.f && ws_size < WS_NEED)
      sent = 16.0f * (float)(ws_size >> 20);
  }
  if (sent != 0.f){
    hipLaunchKernelGGL(k_sent, dim3(1), dim3(64), 0, stream, out, sent);
    return;
  }

  const float* xref  = (const float*)d_in[0];
  const float* xnb   = (const float*)d_in[1];
  const float* bflow = (const float*)d_in[2];
  const float* bfeat = (const float*)d_in[3];
  const float* w0 = (const float*)d_in[4];
  const float* b0 = (const float*)d_in[5];
  const float* w1 = (const float*)d_in[6];
  const float* b1 = (const float*)d_in[7];
  const float* w2 = (const float*)d_in[8];
  const float* b2 = (const float*)d_in[9];
  const float* wf = (const float*)d_in[10];
  const float* bf = (const float*)d_in[11];
  char* ws = (char*)d_ws;
  u16* wse   = (u16*)d_ws;
  u16* inpT  = (u16*)(ws + OFF_INPT);
  u16* hT    = (u16*)(ws + OFF_HT);
  u16* t1T   = (u16*)(ws + OFF_T1);
  u16* feaT  = (u16*)(ws + OFF_FEA);
  u16* xrefT = (u16*)(ws + OFF_XREFT);
  u16* xnbT  = (u16*)(ws + OFF_XNBT);

  hipLaunchKernelGGL(k_prep, dim3(1143, 4), dim3(256), 0, stream,
                     xref, xnb, bflow, bfeat, w0, w1, w2, wf, ws);
  hipLaunchKernelGGL(k_corr_mfma, dim3(1024, 4), dim3(256), 0, stream, xrefT, xnbT, ws);
  hipLaunchKernelGGL(k_conv0, dim3(256, 4), dim3(256), 0, stream, inpT, wse + E_WT0, b0, hT);
  hipLaunchKernelGGL((k_conv32<2, 0>), dim3(256, 4), dim3(256), 0, stream,
                     hT, wse + E_WT1, b1, t1T, (float*)nullptr, (const u16*)nullptr);
  hipLaunchKernelGGL((k_conv32<2, 1>), dim3(256, 4), dim3(256), 0, stream,
                     t1T, wse + E_WT2, b2, feaT, out, hT);
  hipLaunchKernelGGL((k_conv32<1, 2>), dim3(256, 4), dim3(256), 0, stream,
                     feaT, wse + E_WTF, bf, (u16*)nullptr, out, (const u16*)nullptr);
}